// Round 14
// baseline (839.269 us; speedup 1.0000x reference)
//
#include <hip/hip_runtime.h>
#include <hip/hip_bf16.h>
#include <stdint.h>

#define M_DIM 8192
#define K_DIM 512
#define N_DIM 32000

typedef short bf16x8 __attribute__((ext_vector_type(8)));
typedef float f32x4 __attribute__((ext_vector_type(4)));
typedef unsigned short u16;

__device__ __forceinline__ u16 f2bf(float f) {
  union { float f; uint32_t u; } v; v.f = f;
  uint32_t r = (v.u + 0x7fffu + ((v.u >> 16) & 1u)) >> 16;  // RNE
  return (u16)r;
}

// ---------------- Kernel 0: zero the column-sumsq accumulator ----------------
__global__ void k_zero(float* __restrict__ cn) {
  cn[blockIdx.x * 256 + threadIdx.x] = 0.f;
}

// ---------------- Kernel 1: row-l2norm of x -> bf16, one wave per row ----------------
__global__ void k_xnorm(const float* __restrict__ x, u16* __restrict__ xn) {
  int row = (blockIdx.x * blockDim.x + threadIdx.x) >> 6;
  int lane = threadIdx.x & 63;
  const float4* rp = (const float4*)(x + (size_t)row * K_DIM);
  float4 a = rp[lane];
  float4 b = rp[lane + 64];
  float s = a.x*a.x + a.y*a.y + a.z*a.z + a.w*a.w
          + b.x*b.x + b.y*b.y + b.z*b.z + b.w*b.w;
#pragma unroll
  for (int off = 32; off > 0; off >>= 1) s += __shfl_xor(s, off, 64);
  float r = rsqrtf(fmaxf(s, 1e-12f));
  ushort4 o0 = make_ushort4(f2bf(a.x*r), f2bf(a.y*r), f2bf(a.z*r), f2bf(a.w*r));
  ushort4 o1 = make_ushort4(f2bf(b.x*r), f2bf(b.y*r), f2bf(b.z*r), f2bf(b.w*r));
  ushort4* dst = (ushort4*)(xn + (size_t)row * K_DIM);
  dst[lane] = o0;
  dst[lane + 64] = o1;
}

// ---------------- Kernel 2: transpose + cast (UNNORMALIZED) + fused col-sumsq ----------------
__global__ void k_wtrans(const float* __restrict__ w, float* __restrict__ cn,
                         u16* __restrict__ wT) {
  __shared__ u16 tile[64][68];
  int c0 = blockIdx.x * 64;
  int r0 = blockIdx.y * 64;
  int tc = threadIdx.x & 63;
  int tw = threadIdx.x >> 6;  // 0..3
  float s = 0.f;
#pragma unroll
  for (int i = 0; i < 16; ++i) {
    int r = i * 4 + tw;
    float v = w[(size_t)(r0 + r) * N_DIM + c0 + tc];
    s = fmaf(v, v, s);
    tile[tc][r] = f2bf(v);
  }
  atomicAdd(&cn[c0 + tc], s);
  __syncthreads();
  int cc = threadIdx.x >> 4;        // 0..15
  int rr = (threadIdx.x & 15) * 4;  // 0..60
#pragma unroll
  for (int i = 0; i < 4; ++i) {
    int c = cc + i * 16;
    ushort4 v = *(const ushort4*)&tile[c][rr];
    *(ushort4*)(wT + (size_t)(c0 + c) * K_DIM + r0 + rr) = v;
  }
}

// ---------------- Kernel 3: ZERO-LDS BARRIER-FREE 128x128 GEMM ----------------
// No __shared__, no __syncthreads, no global_load_lds. Fragments load directly
// global->VGPR from the L2-banded panels (A 1 MB/XCD fixed; B walked bn+=8).
// Fully-unrolled K (8 kt x {16 loads + 32 MFMA}) lets the compiler emit counted
// vmcnt and prefetch across kt. Waves never sync: store bursts, load stalls and
// MFMA of the 8 waves/CU (2 blocks) overlap freely -- the drain pathology that
// pinned R2..R13 at >=356us cannot occur.
__global__ __launch_bounds__(256, 2) void k_gemm(const u16* __restrict__ A,
                                                 const u16* __restrict__ Bt,
                                                 const float* __restrict__ cn,
                                                 float* __restrict__ C) {
  const int b = blockIdx.x;
  const int xcd = b & 7;
  const int blk = b >> 3;              // 0..63 worker within XCD
  const int bm = xcd * 8 + (blk & 7);  // FIXED per worker
  const int bn0 = blk >> 3;            // 0..7
  const int cnt = (bn0 < 2) ? 32 : 31; // bn = bn0 + 8*ti < 250

  const int tid = threadIdx.x;
  const int lane = tid & 63;
  const int w = tid >> 6;   // 0..3
  const int wr = w >> 1;    // 0..1 (64-row half)
  const int wc = w & 1;     // 0..1 (64-col half)
  const int la = lane & 15;
  const int lk = lane >> 4; // 0..3

  // per-m A base pointers (A rows fixed for the whole block lifetime)
  const u16* aB[4];
#pragma unroll
  for (int m = 0; m < 4; ++m)
    aB[m] = A + (size_t)(bm * 128 + wr * 64 + m * 16 + la) * K_DIM + lk * 8;

  int bn = bn0;
  const size_t brow = (size_t)(wc * 64 + la) * K_DIM + lk * 8;  // + n*16*K
  constexpr size_t BSTEP = (size_t)8 * 128 * K_DIM;  // bn += 8
  const u16* bP = Bt + (size_t)(bn * 128) * K_DIM + brow;

  const size_t crow0 = (size_t)bm * 128 + wr * 64 + lk * 4;

  f32x4 acc[4][4] = {};

  for (int ti = 0; ti < cnt; ++ti) {
#pragma unroll
    for (int kt = 0; kt < 8; ++kt) {
      bf16x8 af[4][2], bf[4][2];
#pragma unroll
      for (int m = 0; m < 4; ++m) {
        af[m][0] = *(const bf16x8*)(aB[m] + kt * 64);
        af[m][1] = *(const bf16x8*)(aB[m] + kt * 64 + 32);
      }
#pragma unroll
      for (int n = 0; n < 4; ++n) {
        bf[n][0] = *(const bf16x8*)(bP + (size_t)n * 16 * K_DIM + kt * 64);
        bf[n][1] = *(const bf16x8*)(bP + (size_t)n * 16 * K_DIM + kt * 64 + 32);
      }
#pragma unroll
      for (int m = 0; m < 4; ++m)
#pragma unroll
        for (int n = 0; n < 4; ++n) {
          acc[m][n] = __builtin_amdgcn_mfma_f32_16x16x32_bf16(af[m][0], bf[n][0], acc[m][n], 0, 0, 0);
          acc[m][n] = __builtin_amdgcn_mfma_f32_16x16x32_bf16(af[m][1], bf[n][1], acc[m][n], 0, 0, 0);
        }
    }

    // ---- tile epilogue: scale by rsqrt(col sumsq), fire-and-forget NT stores ----
    {
      const int ccol0 = bn * 128 + wc * 64 + la;
      float rs[4];
#pragma unroll
      for (int n = 0; n < 4; ++n)
        rs[n] = rsqrtf(fmaxf(cn[ccol0 + n * 16], 1e-12f));
#pragma unroll
      for (int m = 0; m < 4; ++m)
#pragma unroll
        for (int j = 0; j < 4; ++j) {
          float* cp = C + (crow0 + m * 16 + j) * N_DIM + ccol0;
#pragma unroll
          for (int n = 0; n < 4; ++n)
            __builtin_nontemporal_store(acc[m][n][j] * rs[n], cp + n * 16);
        }
#pragma unroll
      for (int m = 0; m < 4; ++m)
#pragma unroll
        for (int n = 0; n < 4; ++n)
          acc[m][n] = (f32x4){0.f, 0.f, 0.f, 0.f};
    }

    bn += 8;
    bP += BSTEP;
  }
}

// ---------------- launch ----------------
extern "C" void kernel_launch(void* const* d_in, const int* in_sizes, int n_in,
                              void* d_out, int out_size, void* d_ws, size_t ws_size,
                              hipStream_t stream) {
  const float* x = (const float*)d_in[0];   // [8192, 512]
  const float* w = (const float*)d_in[1];   // [512, 32000]
  float* out = (float*)d_out;               // [8192, 32000]

  char* ws = (char*)d_ws;
  float* cn = (float*)ws;                                    // 32000 f32 (sumsq)
  u16* xn = (u16*)(ws + 131072);                             // 8192*512 bf16
  u16* wT = (u16*)(ws + 131072 + (size_t)M_DIM * K_DIM * 2); // 32000*512 bf16

  k_zero<<<N_DIM / 256, 256, 0, stream>>>(cn);
  k_xnorm<<<M_DIM / 4, 256, 0, stream>>>(x, xn);
  k_wtrans<<<dim3(N_DIM / 64, K_DIM / 64), 256, 0, stream>>>(w, cn, wT);
  k_gemm<<<512, 256, 0, stream>>>(xn, wT, cn, out);
}

// Round 15
// 358.283 us; speedup vs baseline: 2.3425x; 2.3425x over previous
//
#include <hip/hip_runtime.h>
#include <hip/hip_bf16.h>
#include <stdint.h>

#define M_DIM 8192
#define K_DIM 512
#define N_DIM 32000

typedef short bf16x8 __attribute__((ext_vector_type(8)));
typedef float f32x4 __attribute__((ext_vector_type(4)));
typedef unsigned short u16;

__device__ __forceinline__ u16 f2bf(float f) {
  union { float f; uint32_t u; } v; v.f = f;
  uint32_t r = (v.u + 0x7fffu + ((v.u >> 16) & 1u)) >> 16;  // RNE
  return (u16)r;
}

// ---------------- Kernel 0: zero the column-sumsq accumulator ----------------
__global__ void k_zero(float* __restrict__ cn) {
  cn[blockIdx.x * 256 + threadIdx.x] = 0.f;
}

// ---------------- Kernel 1: row-l2norm of x -> bf16, one wave per row ----------------
__global__ void k_xnorm(const float* __restrict__ x, u16* __restrict__ xn) {
  int row = (blockIdx.x * blockDim.x + threadIdx.x) >> 6;
  int lane = threadIdx.x & 63;
  const float4* rp = (const float4*)(x + (size_t)row * K_DIM);
  float4 a = rp[lane];
  float4 b = rp[lane + 64];
  float s = a.x*a.x + a.y*a.y + a.z*a.z + a.w*a.w
          + b.x*b.x + b.y*b.y + b.z*b.z + b.w*b.w;
#pragma unroll
  for (int off = 32; off > 0; off >>= 1) s += __shfl_xor(s, off, 64);
  float r = rsqrtf(fmaxf(s, 1e-12f));
  ushort4 o0 = make_ushort4(f2bf(a.x*r), f2bf(a.y*r), f2bf(a.z*r), f2bf(a.w*r));
  ushort4 o1 = make_ushort4(f2bf(b.x*r), f2bf(b.y*r), f2bf(b.z*r), f2bf(b.w*r));
  ushort4* dst = (ushort4*)(xn + (size_t)row * K_DIM);
  dst[lane] = o0;
  dst[lane + 64] = o1;
}

// ---------------- Kernel 2: transpose + cast (UNNORMALIZED) + fused col-sumsq ----------------
__global__ void k_wtrans(const float* __restrict__ w, float* __restrict__ cn,
                         u16* __restrict__ wT) {
  __shared__ u16 tile[64][68];
  int c0 = blockIdx.x * 64;
  int r0 = blockIdx.y * 64;
  int tc = threadIdx.x & 63;
  int tw = threadIdx.x >> 6;  // 0..3
  float s = 0.f;
#pragma unroll
  for (int i = 0; i < 16; ++i) {
    int r = i * 4 + tw;
    float v = w[(size_t)(r0 + r) * N_DIM + c0 + tc];
    s = fmaf(v, v, s);
    tile[tc][r] = f2bf(v);
  }
  atomicAdd(&cn[c0 + tc], s);
  __syncthreads();
  int cc = threadIdx.x >> 4;        // 0..15
  int rr = (threadIdx.x & 15) * 4;  // 0..60
#pragma unroll
  for (int i = 0; i < 4; ++i) {
    int c = cc + i * 16;
    ushort4 v = *(const ushort4*)&tile[c][rr];
    *(ushort4*)(wT + (size_t)(c0 + c) * K_DIM + r0 + rr) = v;
  }
}

// ---------------- Kernel 3: PERSISTENT XCD-BANDED 128x128 GEMM + sibling stagger ----------------
// R9 verbatim (banding, 2 blocks/CU, dbuf, NT stores) with ONE change: the
// odd co-resident sibling (blk&32) sleeps ~12k cycles (~half a tile) before
// starting. Co-scheduled blocks then run ANTI-PHASED: when one drains its
// epilogue store burst at the next tile's vmcnt(0) barrier, the other is
// mid-K-loop issuing MFMA -> write drains are covered and the HBM write
// stream smooths instead of bursting in global lockstep.
__global__ __launch_bounds__(256, 2) void k_gemm(const u16* __restrict__ A,
                                                 const u16* __restrict__ Bt,
                                                 const float* __restrict__ cn,
                                                 float* __restrict__ C) {
  __shared__ u16 sm[2][16384];  // per buf: A [128][64] @0, B [128][64] @8192
  constexpr int BOFF = 8192;

  const int b = blockIdx.x;
  const int xcd = b & 7;
  const int blk = b >> 3;              // 0..63 worker within XCD
  const int bm = xcd * 8 + (blk & 7);  // FIXED per worker
  const int bn0 = blk >> 3;            // 0..7
  const int cnt = (bn0 < 2) ? 32 : 31; // bn = bn0 + 8*ti < 250

  // phase stagger: odd sibling (co-resident with blk-32 on the same CU)
  // sleeps ~12k cycles so the two blocks' epilogue/drain windows anti-align.
  if (blk & 32) {
#pragma unroll
    for (int i = 0; i < 12; ++i) __builtin_amdgcn_s_sleep(15);
  }

  const int tid = threadIdx.x;
  const int lane = tid & 63;
  const int w = tid >> 6;   // 0..3
  const int wr = w >> 1;    // 0..1 (64-row half)
  const int wc = w & 1;     // 0..1 (64-col half)
  const int la = lane & 15;
  const int lk = lane >> 4;
  const int rx = la & 7;
  const int s0 = ((0 + lk) ^ rx) * 8;  // swizzled elem-col, kk=0
  const int s1 = ((4 + lk) ^ rx) * 8;  // swizzled elem-col, kk=32

  // staging (rule #21: linear LDS dest + inverse-swizzled global src)
  const int srow = tid >> 3;                    // 0..31 (+ i*32)
  const int sgl = ((tid & 7) ^ (srow & 7)) * 8; // pre-swizzled global elem col
  const int ldst = srow * 64 + (tid & 7) * 8;   // linear LDS elem offset
  const int arow0 = (wr * 64 + la) * 64;        // + m*1024
  const int brow0 = (wc * 64 + la) * 64;        // + n*1024

  const u16* ag = A + (size_t)(bm * 128 + srow) * K_DIM + sgl;  // fixed all run
  int bn = bn0;
  const u16* bg = Bt + (size_t)(bn * 128 + srow) * K_DIM + sgl;
  constexpr size_t BSTEP = (size_t)8 * 128 * K_DIM;  // bn += 8

  f32x4 acc[4][4] = {};

#define GLL(p, eoff)                                                              \
  __builtin_amdgcn_global_load_lds(                                              \
      (const __attribute__((address_space(1))) void*)(p),                        \
      (__attribute__((address_space(3))) void*)&sm[0][(eoff)], 16, 0, 0)

  // prologue: stage (tile0, kt=0) into buf 0
#pragma unroll
  for (int i = 0; i < 4; ++i) GLL(ag + (size_t)i * 32 * K_DIM, i * 2048 + ldst);
#pragma unroll
  for (int i = 0; i < 4; ++i) GLL(bg + (size_t)i * 32 * K_DIM, BOFF + i * 2048 + ldst);
  __syncthreads();

  for (int ti = 0; ti < cnt; ++ti) {
    const bool last_tile = (ti + 1 == cnt);

    for (int kt = 0; kt < 8; ++kt) {
      const int cur = kt & 1;
      const int nxt = cur ^ 1;
      const bool pf = (kt < 7) || !last_tile;
      const u16* agk = (kt < 7) ? (ag + (kt + 1) * 64) : ag;           // next tile: same A panel
      const u16* bgk = (kt < 7) ? (bg + (kt + 1) * 64) : (bg + BSTEP); // next tile: bn+8

      // stage next K-step (issue early; drained by the kt-end __syncthreads)
      if (pf) {
        const int nb = nxt * 16384;
#pragma unroll
        for (int i = 0; i < 4; ++i) GLL(agk + (size_t)i * 32 * K_DIM, nb + i * 2048 + ldst);
#pragma unroll
        for (int i = 0; i < 4; ++i) GLL(bgk + (size_t)i * 32 * K_DIM, nb + BOFF + i * 2048 + ldst);
      }

      // read all fragments of the current buffer
      bf16x8 af[4][2], bf[4][2];
#pragma unroll
      for (int m = 0; m < 4; ++m) {
        af[m][0] = *(const bf16x8*)&sm[cur][arow0 + m * 1024 + s0];
        af[m][1] = *(const bf16x8*)&sm[cur][arow0 + m * 1024 + s1];
      }
#pragma unroll
      for (int n = 0; n < 4; ++n) {
        bf[n][0] = *(const bf16x8*)&sm[cur][BOFF + brow0 + n * 1024 + s0];
        bf[n][1] = *(const bf16x8*)&sm[cur][BOFF + brow0 + n * 1024 + s1];
      }

#pragma unroll
      for (int m = 0; m < 4; ++m)
#pragma unroll
        for (int n = 0; n < 4; ++n) {
          acc[m][n] = __builtin_amdgcn_mfma_f32_16x16x32_bf16(af[m][0], bf[n][0], acc[m][n], 0, 0, 0);
          acc[m][n] = __builtin_amdgcn_mfma_f32_16x16x32_bf16(af[m][1], bf[n][1], acc[m][n], 0, 0, 0);
        }

      __syncthreads();  // buf[nxt] staged + all reads of buf[cur] done
    }

    // ---- tile epilogue: scale by rsqrt(col sumsq), fire-and-forget NT stores ----
    {
      const size_t crow0 = (size_t)bm * 128 + wr * 64 + lk * 4;
      const int ccol0 = bn * 128 + wc * 64 + la;
      float rs[4];
#pragma unroll
      for (int n = 0; n < 4; ++n)
        rs[n] = rsqrtf(fmaxf(cn[ccol0 + n * 16], 1e-12f));
#pragma unroll
      for (int m = 0; m < 4; ++m)
#pragma unroll
        for (int j = 0; j < 4; ++j) {
          float* cp = C + (crow0 + m * 16 + j) * N_DIM + ccol0;
#pragma unroll
          for (int n = 0; n < 4; ++n)
            __builtin_nontemporal_store(acc[m][n][j] * rs[n], cp + n * 16);
        }
#pragma unroll
      for (int m = 0; m < 4; ++m)
#pragma unroll
        for (int n = 0; n < 4; ++n)
          acc[m][n] = (f32x4){0.f, 0.f, 0.f, 0.f};
    }

    bn += 8;
    bg += BSTEP;
  }
#undef GLL
}

// ---------------- launch ----------------
extern "C" void kernel_launch(void* const* d_in, const int* in_sizes, int n_in,
                              void* d_out, int out_size, void* d_ws, size_t ws_size,
                              hipStream_t stream) {
  const float* x = (const float*)d_in[0];   // [8192, 512]
  const float* w = (const float*)d_in[1];   // [512, 32000]
  float* out = (float*)d_out;               // [8192, 32000]

  char* ws = (char*)d_ws;
  float* cn = (float*)ws;                                    // 32000 f32 (sumsq)
  u16* xn = (u16*)(ws + 131072);                             // 8192*512 bf16
  u16* wT = (u16*)(ws + 131072 + (size_t)M_DIM * K_DIM * 2); // 32000*512 bf16

  k_zero<<<N_DIM / 256, 256, 0, stream>>>(cn);
  k_xnorm<<<M_DIM / 4, 256, 0, stream>>>(x, xn);
  k_wtrans<<<dim3(N_DIM / 64, K_DIM / 64), 256, 0, stream>>>(w, cn, wT);
  k_gemm<<<512, 256, 0, stream>>>(xn, wT, cn, out);
}